// Round 1
// baseline (280.198 us; speedup 1.0000x reference)
//
#include <hip/hip_runtime.h>
#include <cstddef>

#define T_LEN 200
#define BATCH 4096
#define EMBD  25
#define HD    25
#define WCNT  50000

__device__ __forceinline__ float frcp(float x) {
#if __has_builtin(__builtin_amdgcn_rcpf)
    return __builtin_amdgcn_rcpf(x);
#else
    return 1.0f / x;
#endif
}

__device__ __forceinline__ float fsig(float x) {
    float e = __expf(-x);
    return frcp(1.0f + e);
}
__device__ __forceinline__ float ftanh_(float x) {
    float e = __expf(-2.0f * x);
    return (1.0f - e) * frcp(1.0f + e);
}

// embP[dir][w][g] = b_ih_d[g] + sum_j w_ih_d[g][j] * emb[w][j]
// thread = (dir, w, i) computes g = i, 25+i, 50+i
__global__ __launch_bounds__(256) void embp_kernel(
    const float* __restrict__ emb,
    const float* __restrict__ w_ih_f, const float* __restrict__ b_ih_f,
    const float* __restrict__ w_ih_b, const float* __restrict__ b_ih_b,
    float* __restrict__ embP)
{
    int tid = blockIdx.x * 256 + threadIdx.x;
    if (tid >= 2 * WCNT * HD) return;
    int i   = tid % HD;
    int w   = (tid / HD) % WCNT;
    int dir = tid / (HD * WCNT);
    const float* wih = dir ? w_ih_b : w_ih_f;
    const float* bih = dir ? b_ih_b : b_ih_f;
    const float* er  = emb + (size_t)w * EMBD;
    const float* w0  = wih + (0 * HD + i) * EMBD;
    const float* w1  = wih + (1 * HD + i) * EMBD;
    const float* w2  = wih + (2 * HD + i) * EMBD;
    float a0 = bih[i], a1 = bih[HD + i], a2 = bih[2 * HD + i];
    #pragma unroll
    for (int j = 0; j < EMBD; ++j) {
        float x = er[j];
        a0 = fmaf(w0[j], x, a0);
        a1 = fmaf(w1[j], x, a1);
        a2 = fmaf(w2[j], x, a2);
    }
    float* o = embP + ((size_t)dir * WCNT + w) * 75;
    o[i] = a0; o[i + 25] = a1; o[i + 50] = a2;
}

// One 32-lane half-wave per (batch, dir) chain. Block = 256 threads = 8 chains.
template<bool USE_EMBP>
__global__ __launch_bounds__(256) void gru_kernel(
    const int*   __restrict__ input,
    const float* __restrict__ hidden,
    const float* __restrict__ emb,
    const float* __restrict__ w_hh_f, const float* __restrict__ b_hh_f,
    const float* __restrict__ w_ih_f, const float* __restrict__ b_ih_f,
    const float* __restrict__ w_hh_b, const float* __restrict__ b_hh_b,
    const float* __restrict__ w_ih_b, const float* __restrict__ b_ih_b,
    const float* __restrict__ embP,
    float* __restrict__ out)
{
    __shared__ float4 hsh4[8][7];   // [chain slot][jblock], 28 floats/chain (pad 25->28)
    __shared__ float4 xsh4[8][7];
    float* hshf = (float*)hsh4;
    float* xshf = (float*)xsh4;

    const int wave = threadIdx.x >> 6;
    const int half = (threadIdx.x >> 5) & 1;
    const int sub  = threadIdx.x & 31;
    const int b    = blockIdx.x * 4 + wave;
    const int dir  = half;
    const int csub = sub < 25 ? sub : 0;   // clamp for idle lanes 25..31
    const int c    = wave * 2 + half;

    const float* whh = dir ? w_hh_b : w_hh_f;
    const float* bhh = dir ? b_hh_b : b_hh_f;
    const float* wih = dir ? w_ih_b : w_ih_f;
    const float* bih = dir ? b_ih_b : b_ih_f;

    // recurrent weight rows for this lane's h-dim, zero-padded to 28
    float wg0[28], wg1[28], wg2[28];
    #pragma unroll
    for (int j = 0; j < 28; ++j) {
        wg0[j] = (j < 25) ? whh[(0 * 25 + csub) * 25 + j] : 0.0f;
        wg1[j] = (j < 25) ? whh[(1 * 25 + csub) * 25 + j] : 0.0f;
        wg2[j] = (j < 25) ? whh[(2 * 25 + csub) * 25 + j] : 0.0f;
    }
    const float bh0 = bhh[csub], bh1 = bhh[25 + csub], bh2 = bhh[50 + csub];

    float wi0[28], wi1[28], wi2[28];
    float bx0 = 0.f, bx1 = 0.f, bx2 = 0.f;
    if constexpr (!USE_EMBP) {
        #pragma unroll
        for (int j = 0; j < 28; ++j) {
            wi0[j] = (j < 25) ? wih[(0 * 25 + csub) * 25 + j] : 0.0f;
            wi1[j] = (j < 25) ? wih[(1 * 25 + csub) * 25 + j] : 0.0f;
            wi2[j] = (j < 25) ? wih[(2 * 25 + csub) * 25 + j] : 0.0f;
        }
        bx0 = bih[csub]; bx1 = bih[25 + csub]; bx2 = bih[50 + csub];
    }

    // init h in LDS; pads (25..27) zeroed once and never rewritten
    float h0 = 0.0f;
    if (sub < 25) h0 = hidden[((size_t)dir * BATCH + b) * HD + sub];
    if (sub < 28) hshf[c * 28 + sub] = (sub < 25) ? h0 : 0.0f;
    if constexpr (!USE_EMBP) {
        if (sub >= 25 && sub < 28) xshf[c * 28 + sub] = 0.0f;
    }
    __syncthreads();

    const int* ipt = input + (dir ? (T_LEN - 1) * BATCH : 0) + b;
    const int  istr = dir ? -BATCH : BATCH;

    int idx_c = ipt[0];
    int idx_n = ipt[istr];

    const size_t dirW = (size_t)dir * WCNT;
    float xgc0 = 0.f, xgc1 = 0.f, xgc2 = 0.f, xcur = 0.f;
    if constexpr (USE_EMBP) {
        const float* gp = embP + (dirW + (size_t)idx_c) * 75;
        xgc0 = gp[csub]; xgc1 = gp[csub + 25]; xgc2 = gp[csub + 50];
    } else {
        xcur = emb[(size_t)idx_c * EMBD + csub];
    }

    float hown = h0;
    float ymax = -3.0e38f;

    #pragma unroll 2
    for (int tt = 0; tt < T_LEN; ++tt) {
        // prefetch idx two steps ahead, x-projection one step ahead
        int t2 = (tt + 2 < T_LEN) ? tt + 2 : T_LEN - 1;
        int idx_n2 = ipt[t2 * istr];

        float xgn0 = 0.f, xgn1 = 0.f, xgn2 = 0.f, xnext = 0.f;
        if constexpr (USE_EMBP) {
            const float* gp = embP + (dirW + (size_t)idx_n) * 75;
            xgn0 = gp[csub]; xgn1 = gp[csub + 25]; xgn2 = gp[csub + 50];
        } else {
            xnext = emb[(size_t)idx_n * EMBD + csub];
            __builtin_amdgcn_wave_barrier();
            if (sub < 25) xshf[c * 28 + sub] = xcur;
            __builtin_amdgcn_wave_barrier();
        }

        float ar = bh0, az = bh1, an = bh2;
        float axr = bx0, axz = bx1, axn = bx2;
        #pragma unroll
        for (int jb = 0; jb < 7; ++jb) {
            float4 hv = hsh4[c][jb];
            ar = fmaf(wg0[4*jb+0], hv.x, ar); ar = fmaf(wg0[4*jb+1], hv.y, ar);
            ar = fmaf(wg0[4*jb+2], hv.z, ar); ar = fmaf(wg0[4*jb+3], hv.w, ar);
            az = fmaf(wg1[4*jb+0], hv.x, az); az = fmaf(wg1[4*jb+1], hv.y, az);
            az = fmaf(wg1[4*jb+2], hv.z, az); az = fmaf(wg1[4*jb+3], hv.w, az);
            an = fmaf(wg2[4*jb+0], hv.x, an); an = fmaf(wg2[4*jb+1], hv.y, an);
            an = fmaf(wg2[4*jb+2], hv.z, an); an = fmaf(wg2[4*jb+3], hv.w, an);
            if constexpr (!USE_EMBP) {
                float4 xv = xsh4[c][jb];
                axr = fmaf(wi0[4*jb+0], xv.x, axr); axr = fmaf(wi0[4*jb+1], xv.y, axr);
                axr = fmaf(wi0[4*jb+2], xv.z, axr); axr = fmaf(wi0[4*jb+3], xv.w, axr);
                axz = fmaf(wi1[4*jb+0], xv.x, axz); axz = fmaf(wi1[4*jb+1], xv.y, axz);
                axz = fmaf(wi1[4*jb+2], xv.z, axz); axz = fmaf(wi1[4*jb+3], xv.w, axz);
                axn = fmaf(wi2[4*jb+0], xv.x, axn); axn = fmaf(wi2[4*jb+1], xv.y, axn);
                axn = fmaf(wi2[4*jb+2], xv.z, axn); axn = fmaf(wi2[4*jb+3], xv.w, axn);
            }
        }

        float pr, pz, pn_pre;
        if constexpr (USE_EMBP) { pr = xgc0 + ar; pz = xgc1 + az; }
        else                    { pr = axr + ar;  pz = axz + az; }
        float r = fsig(pr);
        float z = fsig(pz);
        if constexpr (USE_EMBP) pn_pre = fmaf(r, an, xgc2);
        else                    pn_pre = fmaf(r, an, axn);
        float n = ftanh_(pn_pre);
        float hnew = fmaf(z, hown - n, n);
        ymax = fmaxf(ymax, hnew);

        __builtin_amdgcn_wave_barrier();
        if (sub < 25) hshf[c * 28 + sub] = hnew;   // in-order per-wave DS => next reads see it
        __builtin_amdgcn_wave_barrier();

        hown = hnew;
        xgc0 = xgn0; xgc1 = xgn1; xgc2 = xgn2; xcur = xnext;
        idx_c = idx_n; idx_n = idx_n2;
    }

    if (sub < 25) {
        out[(size_t)b * 50 + dir * 25 + sub] = ymax;                     // y = max over t
        out[204800 + ((size_t)dir * BATCH + b) * HD + sub] = hown;       // final hidden
    }
}

extern "C" void kernel_launch(void* const* d_in, const int* in_sizes, int n_in,
                              void* d_out, int out_size, void* d_ws, size_t ws_size,
                              hipStream_t stream) {
    const int*   input  = (const int*)  d_in[0];
    const float* hidden = (const float*)d_in[1];
    const float* emb    = (const float*)d_in[2];
    const float* w_ih_f = (const float*)d_in[3];
    const float* w_hh_f = (const float*)d_in[4];
    const float* b_ih_f = (const float*)d_in[5];
    const float* b_hh_f = (const float*)d_in[6];
    const float* w_ih_b = (const float*)d_in[7];
    const float* w_hh_b = (const float*)d_in[8];
    const float* b_ih_b = (const float*)d_in[9];
    const float* b_hh_b = (const float*)d_in[10];
    float* out = (float*)d_out;

    const size_t embp_bytes = (size_t)2 * WCNT * 75 * sizeof(float);  // 30 MB
    if (ws_size >= embp_bytes) {
        float* embP = (float*)d_ws;
        int total = 2 * WCNT * HD;
        embp_kernel<<<(total + 255) / 256, 256, 0, stream>>>(
            emb, w_ih_f, b_ih_f, w_ih_b, b_ih_b, embP);
        gru_kernel<true><<<BATCH / 4, 256, 0, stream>>>(
            input, hidden, emb,
            w_hh_f, b_hh_f, w_ih_f, b_ih_f,
            w_hh_b, b_hh_b, w_ih_b, b_ih_b,
            embP, out);
    } else {
        gru_kernel<false><<<BATCH / 4, 256, 0, stream>>>(
            input, hidden, emb,
            w_hh_f, b_hh_f, w_ih_f, b_ih_f,
            w_hh_b, b_hh_b, w_ih_b, b_ih_b,
            nullptr, out);
    }
}

// Round 2
// 267.951 us; speedup vs baseline: 1.0457x; 1.0457x over previous
//
#include <hip/hip_runtime.h>
#include <cstddef>

#define T_LEN 200
#define BATCH 4096
#define EMBD  25
#define HD    25
#define WCNT  50000

__device__ __forceinline__ float frcp(float x) {
#if __has_builtin(__builtin_amdgcn_rcpf)
    return __builtin_amdgcn_rcpf(x);
#else
    return 1.0f / x;
#endif
}

__device__ __forceinline__ float fsig(float x) {
    float e = __expf(-x);
    return frcp(1.0f + e);
}
__device__ __forceinline__ float ftanh_(float x) {
    float e = __expf(-2.0f * x);
    return (1.0f - e) * frcp(1.0f + e);
}

// embP[dir][w][i*3 + {0,1,2}] = (r,z,n) pre-activations of word w at h-dim i:
//   b_ih[g] + sum_j w_ih[g][j] * emb[w][j],  g = i, 25+i, 50+i
// Interleaved so one lane's 3 values are 12 contiguous bytes (dwordx3 gather).
__global__ __launch_bounds__(256) void embp_kernel(
    const float* __restrict__ emb,
    const float* __restrict__ w_ih_f, const float* __restrict__ b_ih_f,
    const float* __restrict__ w_ih_b, const float* __restrict__ b_ih_b,
    float* __restrict__ embP)
{
    int tid = blockIdx.x * 256 + threadIdx.x;
    if (tid >= 2 * WCNT * HD) return;
    int i   = tid % HD;
    int w   = (tid / HD) % WCNT;
    int dir = tid / (HD * WCNT);
    const float* wih = dir ? w_ih_b : w_ih_f;
    const float* bih = dir ? b_ih_b : b_ih_f;
    const float* er  = emb + (size_t)w * EMBD;
    const float* w0  = wih + (0 * HD + i) * EMBD;
    const float* w1  = wih + (1 * HD + i) * EMBD;
    const float* w2  = wih + (2 * HD + i) * EMBD;
    float a0 = bih[i], a1 = bih[HD + i], a2 = bih[2 * HD + i];
    #pragma unroll
    for (int j = 0; j < EMBD; ++j) {
        float x = er[j];
        a0 = fmaf(w0[j], x, a0);
        a1 = fmaf(w1[j], x, a1);
        a2 = fmaf(w2[j], x, a2);
    }
    float* o = embP + ((size_t)dir * WCNT + w) * 75 + i * 3;
    o[0] = a0; o[1] = a1; o[2] = a2;
}

// One 32-lane half-wave per (batch, dir) chain. Block = 256 threads = 8 chains.
// launch_bounds(256,4): cap VGPR at 128 so the 75 W_hh weights stay resident
// across the 200-step loop (VGPR=60 last round => compiler re-loaded them per step).
__global__ __launch_bounds__(256, 4) void gru_embp_kernel(
    const int*   __restrict__ input,
    const float* __restrict__ hidden,
    const float* __restrict__ w_hh_f, const float* __restrict__ b_hh_f,
    const float* __restrict__ w_hh_b, const float* __restrict__ b_hh_b,
    const float* __restrict__ embP,
    float* __restrict__ out)
{
    __shared__ float hsh[8][28];   // 112 B/chain keeps float4 alignment

    const int wave = threadIdx.x >> 6;
    const int half = (threadIdx.x >> 5) & 1;
    const int sub  = threadIdx.x & 31;
    const int b    = blockIdx.x * 4 + wave;
    const int dir  = half;
    const int csub = sub < 25 ? sub : 0;   // clamp idle lanes 25..31
    const int c    = wave * 2 + half;

    const float* whh = dir ? w_hh_b : w_hh_f;
    const float* bhh = dir ? b_hh_b : b_hh_f;

    // this lane's 3 recurrent weight rows: 75 registers, loop-invariant
    float wg0[25], wg1[25], wg2[25];
    #pragma unroll
    for (int j = 0; j < 25; ++j) {
        wg0[j] = whh[(0 * 25 + csub) * 25 + j];
        wg1[j] = whh[(1 * 25 + csub) * 25 + j];
        wg2[j] = whh[(2 * 25 + csub) * 25 + j];
    }
    const float bh0 = bhh[csub], bh1 = bhh[25 + csub], bh2 = bhh[50 + csub];

    float h0 = 0.0f;
    if (sub < 25) h0 = hidden[((size_t)dir * BATCH + b) * HD + sub];
    if (sub < 25) hsh[c][sub] = h0;
    __syncthreads();

    const int* ipt  = input + (dir ? (T_LEN - 1) * BATCH : 0) + b;
    const int  istr = dir ? -BATCH : BATCH;

    // idx pipeline 4 deep, gather pipeline 2 deep
    int ia = ipt[0];
    int ib_ = ipt[istr];
    int ic = ipt[2 * istr];
    int id_ = ipt[3 * istr];

    const float* tbl = embP + (size_t)dir * WCNT * 75 + csub * 3;

    float xa0, xa1, xa2, xb0, xb1, xb2;
    {
        const float* p = tbl + (size_t)ia * 75;
        xa0 = p[0]; xa1 = p[1]; xa2 = p[2];        // for t
        const float* q = tbl + (size_t)ib_ * 75;
        xb0 = q[0]; xb1 = q[1]; xb2 = q[2];        // for t+1
    }

    float hown = h0;
    float ymax = -3.0e38f;
    const float4* h4 = (const float4*)(&hsh[c][0]);

    #pragma unroll 2
    for (int tt = 0; tt < T_LEN; ++tt) {
        // issue gather for t+2 (idx already resident), then refill idx for t+4
        float xc0, xc1, xc2;
        {
            const float* p = tbl + (size_t)ic * 75;
            xc0 = p[0]; xc1 = p[1]; xc2 = p[2];
        }
        ic = id_;
        int t4 = (tt + 4 < T_LEN) ? tt + 4 : T_LEN - 1;
        id_ = ipt[t4 * istr];

        float ar = bh0, az = bh1, an = bh2;
        #pragma unroll
        for (int jb = 0; jb < 6; ++jb) {
            float4 hv = h4[jb];
            ar = fmaf(wg0[4*jb+0], hv.x, ar); ar = fmaf(wg0[4*jb+1], hv.y, ar);
            ar = fmaf(wg0[4*jb+2], hv.z, ar); ar = fmaf(wg0[4*jb+3], hv.w, ar);
            az = fmaf(wg1[4*jb+0], hv.x, az); az = fmaf(wg1[4*jb+1], hv.y, az);
            az = fmaf(wg1[4*jb+2], hv.z, az); az = fmaf(wg1[4*jb+3], hv.w, az);
            an = fmaf(wg2[4*jb+0], hv.x, an); an = fmaf(wg2[4*jb+1], hv.y, an);
            an = fmaf(wg2[4*jb+2], hv.z, an); an = fmaf(wg2[4*jb+3], hv.w, an);
        }
        float h24 = hsh[c][24];
        ar = fmaf(wg0[24], h24, ar);
        az = fmaf(wg1[24], h24, az);
        an = fmaf(wg2[24], h24, an);

        float r = fsig(xa0 + ar);
        float z = fsig(xa1 + az);
        float n = ftanh_(fmaf(r, an, xa2));
        float hnew = fmaf(z, hown - n, n);
        ymax = fmaxf(ymax, hnew);

        __builtin_amdgcn_wave_barrier();
        if (sub < 25) hsh[c][sub] = hnew;   // per-wave in-order DS: next reads see it
        __builtin_amdgcn_wave_barrier();

        hown = hnew;
        xa0 = xb0; xa1 = xb1; xa2 = xb2;
        xb0 = xc0; xb1 = xc1; xb2 = xc2;
    }

    if (sub < 25) {
        out[(size_t)b * 50 + dir * 25 + sub] = ymax;                 // y = max over t
        out[204800 + ((size_t)dir * BATCH + b) * HD + sub] = hown;   // final hidden
    }
}

// Fallback (no workspace): round-1 kernel, computes xg on the fly.
__global__ __launch_bounds__(256) void gru_fallback_kernel(
    const int*   __restrict__ input,
    const float* __restrict__ hidden,
    const float* __restrict__ emb,
    const float* __restrict__ w_hh_f, const float* __restrict__ b_hh_f,
    const float* __restrict__ w_ih_f, const float* __restrict__ b_ih_f,
    const float* __restrict__ w_hh_b, const float* __restrict__ b_hh_b,
    const float* __restrict__ w_ih_b, const float* __restrict__ b_ih_b,
    float* __restrict__ out)
{
    __shared__ float4 hsh4[8][7];
    __shared__ float4 xsh4[8][7];
    float* hshf = (float*)hsh4;
    float* xshf = (float*)xsh4;

    const int wave = threadIdx.x >> 6;
    const int half = (threadIdx.x >> 5) & 1;
    const int sub  = threadIdx.x & 31;
    const int b    = blockIdx.x * 4 + wave;
    const int dir  = half;
    const int csub = sub < 25 ? sub : 0;
    const int c    = wave * 2 + half;

    const float* whh = dir ? w_hh_b : w_hh_f;
    const float* bhh = dir ? b_hh_b : b_hh_f;
    const float* wih = dir ? w_ih_b : w_ih_f;
    const float* bih = dir ? b_ih_b : b_ih_f;

    float wg0[28], wg1[28], wg2[28], wi0[28], wi1[28], wi2[28];
    #pragma unroll
    for (int j = 0; j < 28; ++j) {
        wg0[j] = (j < 25) ? whh[(0 * 25 + csub) * 25 + j] : 0.0f;
        wg1[j] = (j < 25) ? whh[(1 * 25 + csub) * 25 + j] : 0.0f;
        wg2[j] = (j < 25) ? whh[(2 * 25 + csub) * 25 + j] : 0.0f;
        wi0[j] = (j < 25) ? wih[(0 * 25 + csub) * 25 + j] : 0.0f;
        wi1[j] = (j < 25) ? wih[(1 * 25 + csub) * 25 + j] : 0.0f;
        wi2[j] = (j < 25) ? wih[(2 * 25 + csub) * 25 + j] : 0.0f;
    }
    const float bh0 = bhh[csub], bh1 = bhh[25 + csub], bh2 = bhh[50 + csub];
    const float bx0 = bih[csub], bx1 = bih[25 + csub], bx2 = bih[50 + csub];

    float h0 = 0.0f;
    if (sub < 25) h0 = hidden[((size_t)dir * BATCH + b) * HD + sub];
    if (sub < 28) hshf[c * 28 + sub] = (sub < 25) ? h0 : 0.0f;
    if (sub >= 25 && sub < 28) xshf[c * 28 + sub] = 0.0f;
    __syncthreads();

    const int* ipt  = input + (dir ? (T_LEN - 1) * BATCH : 0) + b;
    const int  istr = dir ? -BATCH : BATCH;

    int idx_c = ipt[0];
    int idx_n = ipt[istr];
    float xcur = emb[(size_t)idx_c * EMBD + csub];

    float hown = h0;
    float ymax = -3.0e38f;

    for (int tt = 0; tt < T_LEN; ++tt) {
        int t2 = (tt + 2 < T_LEN) ? tt + 2 : T_LEN - 1;
        int idx_n2 = ipt[t2 * istr];
        float xnext = emb[(size_t)idx_n * EMBD + csub];
        __builtin_amdgcn_wave_barrier();
        if (sub < 25) xshf[c * 28 + sub] = xcur;
        __builtin_amdgcn_wave_barrier();

        float ar = bh0, az = bh1, an = bh2;
        float axr = bx0, axz = bx1, axn = bx2;
        #pragma unroll
        for (int jb = 0; jb < 7; ++jb) {
            float4 hv = hsh4[c][jb];
            float4 xv = xsh4[c][jb];
            ar = fmaf(wg0[4*jb+0], hv.x, ar); ar = fmaf(wg0[4*jb+1], hv.y, ar);
            ar = fmaf(wg0[4*jb+2], hv.z, ar); ar = fmaf(wg0[4*jb+3], hv.w, ar);
            az = fmaf(wg1[4*jb+0], hv.x, az); az = fmaf(wg1[4*jb+1], hv.y, az);
            az = fmaf(wg1[4*jb+2], hv.z, az); az = fmaf(wg1[4*jb+3], hv.w, az);
            an = fmaf(wg2[4*jb+0], hv.x, an); an = fmaf(wg2[4*jb+1], hv.y, an);
            an = fmaf(wg2[4*jb+2], hv.z, an); an = fmaf(wg2[4*jb+3], hv.w, an);
            axr = fmaf(wi0[4*jb+0], xv.x, axr); axr = fmaf(wi0[4*jb+1], xv.y, axr);
            axr = fmaf(wi0[4*jb+2], xv.z, axr); axr = fmaf(wi0[4*jb+3], xv.w, axr);
            axz = fmaf(wi1[4*jb+0], xv.x, axz); axz = fmaf(wi1[4*jb+1], xv.y, axz);
            axz = fmaf(wi1[4*jb+2], xv.z, axz); axz = fmaf(wi1[4*jb+3], xv.w, axz);
            axn = fmaf(wi2[4*jb+0], xv.x, axn); axn = fmaf(wi2[4*jb+1], xv.y, axn);
            axn = fmaf(wi2[4*jb+2], xv.z, axn); axn = fmaf(wi2[4*jb+3], xv.w, axn);
        }

        float r = fsig(axr + ar);
        float z = fsig(axz + az);
        float n = ftanh_(fmaf(r, an, axn));
        float hnew = fmaf(z, hown - n, n);
        ymax = fmaxf(ymax, hnew);

        __builtin_amdgcn_wave_barrier();
        if (sub < 25) hshf[c * 28 + sub] = hnew;
        __builtin_amdgcn_wave_barrier();

        hown = hnew;
        xcur = xnext;
        idx_c = idx_n; idx_n = idx_n2;
    }

    if (sub < 25) {
        out[(size_t)b * 50 + dir * 25 + sub] = ymax;
        out[204800 + ((size_t)dir * BATCH + b) * HD + sub] = hown;
    }
}

extern "C" void kernel_launch(void* const* d_in, const int* in_sizes, int n_in,
                              void* d_out, int out_size, void* d_ws, size_t ws_size,
                              hipStream_t stream) {
    const int*   input  = (const int*)  d_in[0];
    const float* hidden = (const float*)d_in[1];
    const float* emb    = (const float*)d_in[2];
    const float* w_ih_f = (const float*)d_in[3];
    const float* w_hh_f = (const float*)d_in[4];
    const float* b_ih_f = (const float*)d_in[5];
    const float* b_hh_f = (const float*)d_in[6];
    const float* w_ih_b = (const float*)d_in[7];
    const float* w_hh_b = (const float*)d_in[8];
    const float* b_ih_b = (const float*)d_in[9];
    const float* b_hh_b = (const float*)d_in[10];
    float* out = (float*)d_out;

    const size_t embp_bytes = (size_t)2 * WCNT * 75 * sizeof(float);  // 30 MB
    if (ws_size >= embp_bytes) {
        float* embP = (float*)d_ws;
        int total = 2 * WCNT * HD;
        embp_kernel<<<(total + 255) / 256, 256, 0, stream>>>(
            emb, w_ih_f, b_ih_f, w_ih_b, b_ih_b, embP);
        gru_embp_kernel<<<BATCH / 4, 256, 0, stream>>>(
            input, hidden,
            w_hh_f, b_hh_f, w_hh_b, b_hh_b,
            embP, out);
    } else {
        gru_fallback_kernel<<<BATCH / 4, 256, 0, stream>>>(
            input, hidden, emb,
            w_hh_f, b_hh_f, w_ih_f, b_ih_f,
            w_hh_b, b_hh_b, w_ih_b, b_ih_b,
            out);
    }
}